// Round 2
// baseline (453.034 us; speedup 1.0000x reference)
//
#include <hip/hip_runtime.h>
#include <hip/hip_bf16.h>

// DreamAttention on MI355X.
// Math: out = (Q K^T/sqrt(HD)) V Wo^T  (reference discards softmax!)
//     = Q @ NT_b^T  where NT_b[j][h*128+d1] = sum_d2 (K^T V/sqrt(HD))_bh[d1][d2] * Wo[j][h*128+d2]
// B=2, S=2048, D=2048, NH=16, HD=128.

typedef __attribute__((ext_vector_type(8))) short bf16x8s;   // 8 bf16 in 4 VGPRs
typedef __attribute__((ext_vector_type(4))) float f32x4;

__device__ __forceinline__ ushort f2bf(float f) {
    union { float f; unsigned int u; } x; x.f = f;
    unsigned int u = x.u;
    unsigned int r = (u + 0x7fffu + ((u >> 16) & 1u)) >> 16;   // RTN
    return (ushort)r;
}

__device__ __forceinline__ void gload_lds16(const void* g, void* l) {
    __builtin_amdgcn_global_load_lds((__attribute__((address_space(1))) const void*)g,
                                     (__attribute__((address_space(3))) void*)l, 16, 0, 0);
}

// ---------------------------------------------------------------------------
// NT GEMM: C[m][n] = sum_k A[m][k] * B[n][k]  (+ bias[n]), bf16 in, fp32 acc.
// Tile 128x128, BK=32, 256 thr = 4 waves (2x2), each wave 64x64 = 4x4 MFMA frags.
// m97 structure: global_load_lds(16B) staging, 2 barriers per K-step.
// Batched via blockIdx.z: z -> (zb = z/ZH, zh = z%ZH), element offsets via strides.
// ---------------------------------------------------------------------------
template<bool BIAS, bool OBF16>
__global__ __launch_bounds__(256)
void gemm_nt(const ushort* __restrict__ A, const ushort* __restrict__ B,
             const float* __restrict__ bias, void* __restrict__ Cv,
             int K, int lda, int ldb, int ldc, int ZH,
             long sAb, long sAh, long sBb, long sBh, long sCb, long sCh)
{
    __shared__ ushort As[128 * 32];
    __shared__ ushort Bs[128 * 32];

    int z  = blockIdx.z;
    int zb = z / ZH, zh = z - zb * ZH;
    const ushort* Ab = A + (size_t)(sAb * zb + sAh * zh);
    const ushort* Bb = B + (size_t)(sBb * zb + sBh * zh);
    size_t Coff = (size_t)(sCb * zb + sCh * zh);

    int m0 = blockIdx.x * 128, n0 = blockIdx.y * 128;
    int t = threadIdx.x;
    int l = t & 63, w = t >> 6;
    int wm = (w >> 1) * 64, wn = (w & 1) * 64;
    int lr = l & 15, lk = (l >> 4) * 8;

    f32x4 acc[4][4];
#pragma unroll
    for (int i = 0; i < 4; i++)
#pragma unroll
        for (int j = 0; j < 4; j++)
            acc[i][j] = (f32x4){0.f, 0.f, 0.f, 0.f};

    // staging chunk ids (16B per chunk, 4 chunks per 32-elem row)
    int c0 = t, c1 = t + 256;
    int r0 = c0 >> 2, k0c = (c0 & 3) * 8;
    int r1 = c1 >> 2, k1c = (c1 & 3) * 8;

    for (int kt = 0; kt < K; kt += 32) {
        __syncthreads();   // previous compute done -> safe to overwrite LDS
        gload_lds16(Ab + (size_t)(m0 + r0) * lda + kt + k0c, &As[c0 * 8]);
        gload_lds16(Ab + (size_t)(m0 + r1) * lda + kt + k1c, &As[c1 * 8]);
        gload_lds16(Bb + (size_t)(n0 + r0) * ldb + kt + k0c, &Bs[c0 * 8]);
        gload_lds16(Bb + (size_t)(n0 + r1) * ldb + kt + k1c, &Bs[c1 * 8]);
        __syncthreads();   // drains vmcnt -> LDS ready

        bf16x8s af[4], bf[4];
#pragma unroll
        for (int i = 0; i < 4; i++) {
            af[i] = *(const bf16x8s*)&As[(wm + i * 16 + lr) * 32 + lk];
            bf[i] = *(const bf16x8s*)&Bs[(wn + i * 16 + lr) * 32 + lk];
        }
#pragma unroll
        for (int mi = 0; mi < 4; mi++)
#pragma unroll
            for (int ni = 0; ni < 4; ni++)
                acc[mi][ni] = __builtin_amdgcn_mfma_f32_16x16x32_bf16(
                    af[mi], bf[ni], acc[mi][ni], 0, 0, 0);
    }

    int rr = (l >> 4) * 4;   // C/D: col = lane&15, row = (lane>>4)*4 + reg
#pragma unroll
    for (int mi = 0; mi < 4; mi++) {
#pragma unroll
        for (int ni = 0; ni < 4; ni++) {
            int gr = m0 + wm + mi * 16 + rr;
            int gc = n0 + wn + ni * 16 + lr;
            float bv = BIAS ? bias[gc] : 0.f;
#pragma unroll
            for (int r = 0; r < 4; r++) {
                float v = acc[mi][ni][r] + bv;
                size_t off = Coff + (size_t)(gr + r) * ldc + gc;
                if (OBF16) ((ushort*)Cv)[off] = f2bf(v);
                else       ((float*)Cv)[off]  = v;
            }
        }
    }
}

// ---------------------------------------------------------------------------
// RoPE: in-place on K (fp32), Q -> bf16 Qb. thread = (row, head, d<64).
// cos/sin computed directly: angle = pos * 10000^(-d/64); matches table.
// ---------------------------------------------------------------------------
__global__ __launch_bounds__(256)
void rope_qk(const float* __restrict__ Qf, float* __restrict__ Kio,
             const int* __restrict__ pos, ushort* __restrict__ Qb)
{
    int tid = blockIdx.x * 256 + threadIdx.x;   // 4096*1024 total
    int row = tid >> 10;
    int r = tid & 1023;
    int h = r >> 6, d = r & 63;
    int p = pos[row];
    float invf = exp2f((float)d * (-13.287712379549449f / 64.0f));
    float ang = (float)p * invf;
    float s, c;
    sincosf(ang, &s, &c);
    size_t base = (size_t)row * 2048 + h * 128 + d;
    float q1 = Qf[base], q2 = Qf[base + 64];
    Qb[base]      = f2bf(q1 * c - q2 * s);
    Qb[base + 64] = f2bf(q2 * c + q1 * s);
    float k1 = Kio[base], k2 = Kio[base + 64];
    Kio[base]      = k1 * c - k2 * s;
    Kio[base + 64] = k2 * c + k1 * s;
}

// ---------------------------------------------------------------------------
// K^T V partials, fp32 vector. grid (32 bh, 16 s-slices). Block: 256 thr,
// thread grid 16x16, each 8x8 outputs; slice = 128 s-rows staged 32 at a time.
// part[(slice*32 + bh)*16384 + d1*128 + d2]
// ---------------------------------------------------------------------------
__global__ __launch_bounds__(256)
void ktv_partial(const float* __restrict__ Kf, const float* __restrict__ Vf,
                 float* __restrict__ part)
{
    int bh = blockIdx.x;
    int b = bh >> 4, h = bh & 15;
    int s0 = blockIdx.y * 128;
    const float* Kp = Kf + ((size_t)(b * 2048 + s0)) * 2048 + h * 128;
    const float* Vp = Vf + ((size_t)(b * 2048 + s0)) * 2048 + h * 128;

    __shared__ float Ks[32][128];
    __shared__ float Vs[32][128];

    int t = threadIdx.x;
    int tx = t & 15, ty = t >> 4;
    float acc[8][8];
#pragma unroll
    for (int i = 0; i < 8; i++)
#pragma unroll
        for (int j = 0; j < 8; j++) acc[i][j] = 0.f;

    for (int sb = 0; sb < 128; sb += 32) {
        __syncthreads();
#pragma unroll
        for (int i = 0; i < 4; i++) {
            int idx = t + i * 256;          // 1024 float4 chunks per operand
            int rw = idx >> 5, c4 = (idx & 31) * 4;
            *(float4*)&Ks[rw][c4] = *(const float4*)&Kp[(size_t)(sb + rw) * 2048 + c4];
            *(float4*)&Vs[rw][c4] = *(const float4*)&Vp[(size_t)(sb + rw) * 2048 + c4];
        }
        __syncthreads();
        for (int ss = 0; ss < 32; ss++) {
            float kv[8], vv[8];
            *(float4*)&kv[0] = *(const float4*)&Ks[ss][tx * 8];
            *(float4*)&kv[4] = *(const float4*)&Ks[ss][tx * 8 + 4];
            *(float4*)&vv[0] = *(const float4*)&Vs[ss][ty * 8];
            *(float4*)&vv[4] = *(const float4*)&Vs[ss][ty * 8 + 4];
#pragma unroll
            for (int i = 0; i < 8; i++)
#pragma unroll
                for (int j = 0; j < 8; j++)
                    acc[i][j] += kv[i] * vv[j];
        }
    }
    float* pp = part + ((size_t)blockIdx.y * 32 + bh) * 16384;
#pragma unroll
    for (int i = 0; i < 8; i++)
#pragma unroll
        for (int j = 0; j < 8; j++)
            pp[(tx * 8 + i) * 128 + (ty * 8 + j)] = acc[i][j];
}

// Reduce 16 partials -> Mb (bf16), scaled by 1/sqrt(128).
__global__ __launch_bounds__(256)
void reduce_ktv(const float* __restrict__ part, ushort* __restrict__ Mb)
{
    int i = blockIdx.x * 256 + threadIdx.x;   // 32*16384 = 524288
    float s = 0.f;
#pragma unroll
    for (int p = 0; p < 16; p++) s += part[(size_t)p * 524288 + i];
    Mb[i] = f2bf(s * 0.08838834764831845f);
}

// fp32 -> bf16 convert, float4-vectorized.
__global__ __launch_bounds__(256)
void conv_f32_bf16(const float* __restrict__ in, ushort* __restrict__ out, int n4)
{
    int i = blockIdx.x * 256 + threadIdx.x;
    if (i >= n4) return;
    float4 v = ((const float4*)in)[i];
    ushort4 o;
    o.x = f2bf(v.x); o.y = f2bf(v.y); o.z = f2bf(v.z); o.w = f2bf(v.w);
    ((ushort4*)out)[i] = o;
}

// ---------------------------------------------------------------------------
// Workspace layout (bytes) — ~105 MB total:
//   HSB  @ 0         : 16,777,216  (hs bf16 4096x2048)
//   WBUF @ 16777216  :  8,388,608  (one weight bf16, reused Wq/Wk/Wv/Wo)
//   Kf   @ 25165824  : 33,554,432  (fp32, RoPE in place)
//   Vf   @ 58720256  : 33,554,432  (fp32; reused as NT bf16 after ktv)
//   QB   @ 92274688  : 16,777,216  (bf16 RoPE'd Q)
//   MB   @ 109051904 :  1,048,576  (bf16 M, 32x128x128)
// d_out (33,554,432 B) doubles as scratch: fp32 Q (dead after rope), then
// KtV partials (dead after reduce). Final GEMM writes out last — safe, all
// launches are stream-ordered and d_out is re-poisoned before every call.
// ---------------------------------------------------------------------------
extern "C" void kernel_launch(void* const* d_in, const int* in_sizes, int n_in,
                              void* d_out, int out_size, void* d_ws, size_t ws_size,
                              hipStream_t stream)
{
    const float* hs = (const float*)d_in[0];
    const int*  pos = (const int*)d_in[1];
    const float* Wq = (const float*)d_in[2];
    const float* bq = (const float*)d_in[3];
    const float* Wk = (const float*)d_in[4];
    const float* bk = (const float*)d_in[5];
    const float* Wv = (const float*)d_in[6];
    const float* bv = (const float*)d_in[7];
    const float* Wo = (const float*)d_in[8];
    float* out = (float*)d_out;
    char* ws = (char*)d_ws;

    ushort* HSB  = (ushort*)(ws + 0);
    ushort* WBUF = (ushort*)(ws + 16777216);
    float*  Kf   = (float*)(ws + 25165824);
    float*  Vf   = (float*)(ws + 58720256);
    ushort* QB   = (ushort*)(ws + 92274688);
    ushort* MB   = (ushort*)(ws + 109051904);
    float*  Qf   = out;            // d_out as scratch: fp32 Q
    float*  PART = out;            // then ktv partials (Q dead after rope)
    ushort* NT   = (ushort*)Vf;    // V dead after ktv

    dim3 blk(256);
    dim3 gQKV(32, 16, 1);

    conv_f32_bf16<<<8192, blk, 0, stream>>>(hs, HSB, 2097152);

    conv_f32_bf16<<<4096, blk, 0, stream>>>(Wq, WBUF, 1048576);
    gemm_nt<true, false><<<gQKV, blk, 0, stream>>>(HSB, WBUF, bq, Qf,
        2048, 2048, 2048, 2048, 1, 0, 0, 0, 0, 0, 0);

    conv_f32_bf16<<<4096, blk, 0, stream>>>(Wk, WBUF, 1048576);
    gemm_nt<true, false><<<gQKV, blk, 0, stream>>>(HSB, WBUF, bk, Kf,
        2048, 2048, 2048, 2048, 1, 0, 0, 0, 0, 0, 0);

    conv_f32_bf16<<<4096, blk, 0, stream>>>(Wv, WBUF, 1048576);
    gemm_nt<true, false><<<gQKV, blk, 0, stream>>>(HSB, WBUF, bv, Vf,
        2048, 2048, 2048, 2048, 1, 0, 0, 0, 0, 0, 0);

    rope_qk<<<16384, blk, 0, stream>>>(Qf, Kf, pos, QB);

    ktv_partial<<<dim3(32, 16, 1), blk, 0, stream>>>(Kf, Vf, PART);
    reduce_ktv<<<2048, blk, 0, stream>>>(PART, MB);

    conv_f32_bf16<<<4096, blk, 0, stream>>>(Wo, WBUF, 1048576);

    // NT_b[j][h*128+d1] = sum_d2 Wo_b16[j][h*128+d2] * Mb_bh[d1][d2]
    gemm_nt<false, true><<<dim3(16, 1, 32), blk, 0, stream>>>(WBUF, MB, nullptr, NT,
        128, 2048, 128, 2048, 16,
        /*sAb*/0, /*sAh*/128, /*sBb*/262144, /*sBh*/16384, /*sCb*/4194304, /*sCh*/128);

    // out[b] = QB_b @ NT_b^T
    gemm_nt<false, false><<<dim3(16, 16, 2), blk, 0, stream>>>(QB, NT, nullptr, out,
        2048, 2048, 2048, 2048, 1,
        /*sAb*/4194304, 0, /*sBb*/4194304, 0, /*sCb*/4194304, 0);
}

// Round 3
// 408.820 us; speedup vs baseline: 1.1082x; 1.1082x over previous
//
#include <hip/hip_runtime.h>
#include <hip/hip_bf16.h>

// DreamAttention on MI355X.
// Math: out = (Q K^T/sqrt(HD)) V Wo^T  (reference discards softmax!)
//     = Q @ NT_b^T  where NT_b[j][h*128+d1] = sum_d2 (K^T V/sqrt(HD))_bh[d1][d2] * Wo[j][h*128+d2]
// B=2, S=2048, D=2048, NH=16, HD=128.
// Round 3: fused QKV GEMM (N=6144, 1536 blocks = 6/CU), 128x64 final GEMM
// (1024 blocks = 4/CU), bf16 intermediates throughout.

typedef __attribute__((ext_vector_type(8))) short bf16x8s;   // 8 bf16 in 4 VGPRs
typedef __attribute__((ext_vector_type(4))) float f32x4;

__device__ __forceinline__ ushort f2bf(float f) {
    union { float f; unsigned int u; } x; x.f = f;
    unsigned int u = x.u;
    unsigned int r = (u + 0x7fffu + ((u >> 16) & 1u)) >> 16;   // RTN
    return (ushort)r;
}
__device__ __forceinline__ float b2f(ushort u) {
    union { unsigned int u; float f; } x; x.u = ((unsigned int)u) << 16;
    return x.f;
}

__device__ __forceinline__ void gload_lds16(const void* g, void* l) {
    __builtin_amdgcn_global_load_lds((__attribute__((address_space(1))) const void*)g,
                                     (__attribute__((address_space(3))) void*)l, 16, 0, 0);
}

// ---------------------------------------------------------------------------
// NT GEMM: C[m][n] = sum_k A[m][k] * B[n][k]  (+ bias[n]), bf16 in, fp32 acc.
// BN=128: tile 128x128, 4 waves 2x2, each 64x64 = 4x4 frags.
// BN=64 : tile 128x64,  4 waves 4x1, each 32x64 = 2x4 frags (doubles grid for
//         occupancy-starved shapes).
// BK=32, m97 structure: global_load_lds(16B), 2 barriers per K-step.
// Batched via blockIdx.z: z -> (zb=z/ZH, zh=z%ZH), element offsets via strides.
// ---------------------------------------------------------------------------
template<bool BIAS, bool OBF16, int BN>
__global__ __launch_bounds__(256)
void gemm_nt(const ushort* __restrict__ A, const ushort* __restrict__ B,
             const float* __restrict__ bias, void* __restrict__ Cv,
             int K, int lda, int ldb, int ldc, int ZH,
             long sAb, long sAh, long sBb, long sBh, long sCb, long sCh)
{
    __shared__ ushort As[128 * 32];
    __shared__ ushort Bs[BN * 32];

    int z  = blockIdx.z;
    int zb = z / ZH, zh = z - zb * ZH;
    const ushort* Ab = A + (size_t)(sAb * zb + sAh * zh);
    const ushort* Bb = B + (size_t)(sBb * zb + sBh * zh);
    size_t Coff = (size_t)(sCb * zb + sCh * zh);

    int m0 = blockIdx.x * 128, n0 = blockIdx.y * BN;
    int t = threadIdx.x;
    int l = t & 63, w = t >> 6;
    int wm, wn;
    if (BN == 128) { wm = (w >> 1) * 64; wn = (w & 1) * 64; }
    else           { wm = w * 32;        wn = 0; }
    constexpr int FM = (BN == 128) ? 4 : 2;
    constexpr int FN = 4;
    int lr = l & 15, lk = (l >> 4) * 8;

    f32x4 acc[FM][FN];
#pragma unroll
    for (int i = 0; i < FM; i++)
#pragma unroll
        for (int j = 0; j < FN; j++)
            acc[i][j] = (f32x4){0.f, 0.f, 0.f, 0.f};

    // staging chunk ids (16B per chunk, 4 chunks per 32-elem row)
    int c0 = t, c1 = t + 256;
    int r0 = c0 >> 2, k0c = (c0 & 3) * 8;
    int r1 = c1 >> 2, k1c = (c1 & 3) * 8;

    for (int kt = 0; kt < K; kt += 32) {
        __syncthreads();   // previous compute done -> safe to overwrite LDS
        gload_lds16(Ab + (size_t)(m0 + r0) * lda + kt + k0c, &As[c0 * 8]);
        gload_lds16(Ab + (size_t)(m0 + r1) * lda + kt + k1c, &As[c1 * 8]);
        gload_lds16(Bb + (size_t)(n0 + r0) * ldb + kt + k0c, &Bs[c0 * 8]);
        if (BN == 128)
            gload_lds16(Bb + (size_t)(n0 + r1) * ldb + kt + k1c, &Bs[c1 * 8]);
        __syncthreads();   // drains vmcnt -> LDS ready

        bf16x8s af[FM], bf[FN];
#pragma unroll
        for (int i = 0; i < FM; i++)
            af[i] = *(const bf16x8s*)&As[(wm + i * 16 + lr) * 32 + lk];
#pragma unroll
        for (int i = 0; i < FN; i++)
            bf[i] = *(const bf16x8s*)&Bs[(wn + i * 16 + lr) * 32 + lk];
#pragma unroll
        for (int mi = 0; mi < FM; mi++)
#pragma unroll
            for (int ni = 0; ni < FN; ni++)
                acc[mi][ni] = __builtin_amdgcn_mfma_f32_16x16x32_bf16(
                    af[mi], bf[ni], acc[mi][ni], 0, 0, 0);
    }

    int rr = (l >> 4) * 4;   // C/D: col = lane&15, row = (lane>>4)*4 + reg
#pragma unroll
    for (int mi = 0; mi < FM; mi++) {
#pragma unroll
        for (int ni = 0; ni < FN; ni++) {
            int gr = m0 + wm + mi * 16 + rr;
            int gc = n0 + wn + ni * 16 + lr;
            float bv = BIAS ? bias[gc] : 0.f;
#pragma unroll
            for (int r = 0; r < 4; r++) {
                float v = acc[mi][ni][r] + bv;
                size_t off = Coff + (size_t)(gr + r) * ldc + gc;
                if (OBF16) ((ushort*)Cv)[off] = f2bf(v);
                else       ((float*)Cv)[off]  = v;
            }
        }
    }
}

// ---------------------------------------------------------------------------
// RoPE on bf16 QKV buffer [4096][6144] (Q cols 0-2047, K 2048-4095).
// Q -> compact QB [4096][2048]; K in place. Vectorized: thread = (row,h,j),
// handles 8 consecutive d in [0,64) and their pairs d+64.
// angle = pos * 10000^(-d/64); positions < 4096 match the reference table.
// ---------------------------------------------------------------------------
__global__ __launch_bounds__(256)
void rope_qk(ushort* __restrict__ QKV, const int* __restrict__ pos,
             ushort* __restrict__ QB)
{
    int tid = blockIdx.x * 256 + threadIdx.x;   // 4096*16*8 = 524288
    int row = tid >> 7;
    int r = tid & 127;
    int h = r >> 3, j = r & 7;
    int d0 = j * 8;
    float p = (float)pos[row];
    size_t qb = (size_t)row * 6144 + h * 128 + d0;

    bf16x8s q1 = *(const bf16x8s*)&QKV[qb];
    bf16x8s q2 = *(const bf16x8s*)&QKV[qb + 64];
    bf16x8s k1 = *(const bf16x8s*)&QKV[qb + 2048];
    bf16x8s k2 = *(const bf16x8s*)&QKV[qb + 2048 + 64];
    bf16x8s oq1, oq2, ok1, ok2;
#pragma unroll
    for (int i = 0; i < 8; i++) {
        float d = (float)(d0 + i);
        float ang = p * exp2f(d * (-13.287712379549449f / 64.0f));
        float s, c;
        sincosf(ang, &s, &c);
        float a = b2f((ushort)q1[i]), b = b2f((ushort)q2[i]);
        oq1[i] = (short)f2bf(a * c - b * s);
        oq2[i] = (short)f2bf(b * c + a * s);
        float e = b2f((ushort)k1[i]), f = b2f((ushort)k2[i]);
        ok1[i] = (short)f2bf(e * c - f * s);
        ok2[i] = (short)f2bf(f * c + e * s);
    }
    size_t ob = (size_t)row * 2048 + h * 128 + d0;
    *(bf16x8s*)&QB[ob]      = oq1;
    *(bf16x8s*)&QB[ob + 64] = oq2;
    *(bf16x8s*)&QKV[qb + 2048]      = ok1;
    *(bf16x8s*)&QKV[qb + 2048 + 64] = ok2;
}

// ---------------------------------------------------------------------------
// K^T V partials from bf16 QKV buf. grid (32 bh, 16 s-slices). 256 thr,
// thread grid 16x16, each 8x8 outputs; slice = 128 s-rows staged 32 at a time.
// part[(slice*32 + bh)*16384 + d1*128 + d2]  (fp32, lives in d_out)
// ---------------------------------------------------------------------------
__global__ __launch_bounds__(256)
void ktv_partial(const ushort* __restrict__ QKV, float* __restrict__ part)
{
    int bh = blockIdx.x;
    int b = bh >> 4, h = bh & 15;
    int s0 = blockIdx.y * 128;
    const ushort* Kp = QKV + (size_t)(b * 2048 + s0) * 6144 + 2048 + h * 128;
    const ushort* Vp = Kp + 2048;

    __shared__ ushort Ks[32][128];
    __shared__ ushort Vs[32][128];

    int t = threadIdx.x;
    int tx = t & 15, ty = t >> 4;
    float acc[8][8];
#pragma unroll
    for (int i = 0; i < 8; i++)
#pragma unroll
        for (int j = 0; j < 8; j++) acc[i][j] = 0.f;

    for (int sb = 0; sb < 128; sb += 32) {
        __syncthreads();
#pragma unroll
        for (int i = 0; i < 2; i++) {
            int idx = t + i * 256;          // 512 ushort8 chunks per operand
            int rw = idx >> 4, c8 = (idx & 15) * 8;
            *(bf16x8s*)&Ks[rw][c8] = *(const bf16x8s*)&Kp[(size_t)(sb + rw) * 6144 + c8];
            *(bf16x8s*)&Vs[rw][c8] = *(const bf16x8s*)&Vp[(size_t)(sb + rw) * 6144 + c8];
        }
        __syncthreads();
        for (int ss = 0; ss < 32; ss++) {
            bf16x8s kvv = *(const bf16x8s*)&Ks[ss][tx * 8];
            bf16x8s vvv = *(const bf16x8s*)&Vs[ss][ty * 8];
            float kv[8], vv[8];
#pragma unroll
            for (int i = 0; i < 8; i++) { kv[i] = b2f((ushort)kvv[i]); vv[i] = b2f((ushort)vvv[i]); }
#pragma unroll
            for (int i = 0; i < 8; i++)
#pragma unroll
                for (int j = 0; j < 8; j++)
                    acc[i][j] += kv[i] * vv[j];
        }
    }
    float* pp = part + ((size_t)blockIdx.y * 32 + bh) * 16384;
#pragma unroll
    for (int i = 0; i < 8; i++)
#pragma unroll
        for (int j = 0; j < 8; j++)
            pp[(tx * 8 + i) * 128 + (ty * 8 + j)] = acc[i][j];
}

// Reduce 16 partials -> Mb (bf16), scaled by 1/sqrt(128).
__global__ __launch_bounds__(256)
void reduce_ktv(const float* __restrict__ part, ushort* __restrict__ Mb)
{
    int i = blockIdx.x * 256 + threadIdx.x;   // 32*16384 = 524288
    float s = 0.f;
#pragma unroll
    for (int p = 0; p < 16; p++) s += part[(size_t)p * 524288 + i];
    Mb[i] = f2bf(s * 0.08838834764831845f);
}

// fp32 -> bf16 convert, float4-vectorized (hidden states).
__global__ __launch_bounds__(256)
void conv_f32_bf16(const float* __restrict__ in, ushort* __restrict__ out, int n4)
{
    int i = blockIdx.x * 256 + threadIdx.x;
    if (i >= n4) return;
    float4 v = ((const float4*)in)[i];
    ushort4 o;
    o.x = f2bf(v.x); o.y = f2bf(v.y); o.z = f2bf(v.z); o.w = f2bf(v.w);
    ((ushort4*)out)[i] = o;
}

// All four weights -> bf16 in one launch. Wq,Wk,Wv stacked into WQKV
// (6144x2048), Wo into WOB. 4 x 1048576 float4 chunks.
__global__ __launch_bounds__(256)
void conv_weights(const float* __restrict__ w0, const float* __restrict__ w1,
                  const float* __restrict__ w2, const float* __restrict__ w3,
                  ushort* __restrict__ qkv, ushort* __restrict__ wo)
{
    int i = blockIdx.x * 256 + threadIdx.x;   // 4*2^20 chunks
    int id = i >> 20;
    int off = i & 1048575;
    const float* src = (id == 0) ? w0 : (id == 1) ? w1 : (id == 2) ? w2 : w3;
    float4 v = ((const float4*)src)[off];
    ushort4 o;
    o.x = f2bf(v.x); o.y = f2bf(v.y); o.z = f2bf(v.z); o.w = f2bf(v.w);
    if (id < 3) ((ushort4*)qkv)[(size_t)id * 1048576 + off] = o;
    else        ((ushort4*)wo)[off] = o;
}

// Stack bq,bk,bv -> 6144-float buffer.
__global__ __launch_bounds__(256)
void pack_bias(const float* __restrict__ bq, const float* __restrict__ bk,
               const float* __restrict__ bv, float* __restrict__ bqkv)
{
    int i = blockIdx.x * 256 + threadIdx.x;   // 6144
    float v = (i < 2048) ? bq[i] : (i < 4096) ? bk[i - 2048] : bv[i - 4096];
    bqkv[i] = v;
}

// ---------------------------------------------------------------------------
// Workspace (~102 MB):
//   HSB/QB @ 0        : 16,777,216  (hs bf16; reused as QB after QKV GEMM)
//   WQKV/NT@ 16777216 : 25,165,824  (stacked weights bf16; reused as NT)
//   WOB    @ 41943040 :  8,388,608
//   BQKV   @ 50331648 :     24,576
//   QKVB   @ 50356224 : 50,331,648  (bf16 [4096][6144])
//   MB     @100687872 :  1,048,576
// d_out doubles as ktv-partial scratch (33,554,432 B exactly); final GEMM
// writes it last. All launches stream-ordered.
// ---------------------------------------------------------------------------
extern "C" void kernel_launch(void* const* d_in, const int* in_sizes, int n_in,
                              void* d_out, int out_size, void* d_ws, size_t ws_size,
                              hipStream_t stream)
{
    const float* hs = (const float*)d_in[0];
    const int*  pos = (const int*)d_in[1];
    const float* Wq = (const float*)d_in[2];
    const float* bq = (const float*)d_in[3];
    const float* Wk = (const float*)d_in[4];
    const float* bk = (const float*)d_in[5];
    const float* Wv = (const float*)d_in[6];
    const float* bv = (const float*)d_in[7];
    const float* Wo = (const float*)d_in[8];
    float* out = (float*)d_out;
    char* ws = (char*)d_ws;

    ushort* HSB  = (ushort*)(ws + 0);
    ushort* QB   = (ushort*)(ws + 0);           // HSB dead after QKV GEMM
    ushort* WQKV = (ushort*)(ws + 16777216);
    ushort* NT   = (ushort*)(ws + 16777216);    // WQKV dead after QKV GEMM
    ushort* WOB  = (ushort*)(ws + 41943040);
    float*  BQKV = (float*)(ws + 50331648);
    ushort* QKVB = (ushort*)(ws + 50356224);
    ushort* MB   = (ushort*)(ws + 100687872);
    float*  PART = out;                          // d_out as scratch until final

    dim3 blk(256);

    conv_f32_bf16<<<8192, blk, 0, stream>>>(hs, HSB, 2097152);
    conv_weights<<<16384, blk, 0, stream>>>(Wq, Wk, Wv, Wo, WQKV, WOB);
    pack_bias<<<24, blk, 0, stream>>>(bq, bk, bv, BQKV);

    // Fused QKV: [4096x2048] @ [6144x2048]^T -> QKVB [4096][6144] bf16
    gemm_nt<true, true, 128><<<dim3(32, 48, 1), blk, 0, stream>>>(
        HSB, WQKV, BQKV, QKVB, 2048, 2048, 2048, 6144, 1, 0, 0, 0, 0, 0, 0);

    rope_qk<<<2048, blk, 0, stream>>>(QKVB, pos, QB);

    ktv_partial<<<dim3(32, 16, 1), blk, 0, stream>>>(QKVB, PART);
    reduce_ktv<<<2048, blk, 0, stream>>>(PART, MB);

    // NT_b[j][h*128+d1] = sum_d2 Wo_b16[j][h*128+d2] * M_bh[d1][d2]
    gemm_nt<false, true, 128><<<dim3(16, 1, 32), blk, 0, stream>>>(
        WOB, MB, nullptr, NT, 128, 2048, 128, 2048, 16,
        /*sAb*/0, /*sAh*/128, /*sBb*/262144, /*sBh*/16384, /*sCb*/4194304, /*sCh*/128);

    // out[b] = QB_b @ NT_b^T   (128x64 tiles -> 1024 blocks = 4/CU)
    gemm_nt<false, false, 64><<<dim3(16, 32, 2), blk, 0, stream>>>(
        QB, NT, nullptr, out, 2048, 2048, 2048, 2048, 1,
        /*sAb*/4194304, 0, /*sBb*/4194304, 0, /*sCb*/4194304, 0);
}

// Round 4
// 393.152 us; speedup vs baseline: 1.1523x; 1.0399x over previous
//
#include <hip/hip_runtime.h>
#include <hip/hip_bf16.h>

// DreamAttention on MI355X.
// Math: out = (Q K^T/sqrt(HD)) V Wo^T  (reference discards softmax!)
//     = Q @ NT_b^T  where NT_b[j][h*128+d1] = sum_d2 (K^T V/sqrt(HD))_bh[d1][d2] * Wo[j][h*128+d2]
// B=2, S=2048, D=2048, NH=16, HD=128.
// Round 4: 256x256 BK=32 counted-vmcnt pipelined GEMM (4 LDS tile-buffers,
// vmcnt(4) boundaries - never drains), conflict-free XOR chunk swizzle.

typedef __attribute__((ext_vector_type(8))) short bf16x8s;   // 8 bf16 in 4 VGPRs
typedef __attribute__((ext_vector_type(4))) float f32x4;

__device__ __forceinline__ ushort f2bf(float f) {
    union { float f; unsigned int u; } x; x.f = f;
    unsigned int u = x.u;
    unsigned int r = (u + 0x7fffu + ((u >> 16) & 1u)) >> 16;   // RTN
    return (ushort)r;
}
__device__ __forceinline__ float b2f(ushort u) {
    union { unsigned int u; float f; } x; x.u = ((unsigned int)u) << 16;
    return x.f;
}

__device__ __forceinline__ void gload_lds16(const void* g, void* l) {
    __builtin_amdgcn_global_load_lds((__attribute__((address_space(1))) const void*)g,
                                     (__attribute__((address_space(3))) void*)l, 16, 0, 0);
}

// ---------------------------------------------------------------------------
// 256x256 NT GEMM, BK=32, 512 thr (8 waves 2Mx4N), counted-vmcnt pipeline.
// C[m][n] = sum_k A[m][k]*B[n][k] (+bias[n]); bf16 in, fp32 acc.
// LDS: per operand 4 tile-buffers of 16KB (mod-4 by K-tile). Tile layout:
//   logical (r,c): r in [0,256), 16B chunk j in [0,4) of the 64B row.
//   physical: pr=r>>1 rows of 128B; chunk pos = (((r&1)<<2)|j) ^ (pr&7).
//   -> frag ds_read_b128 (16 lanes, same j, consecutive r) hits 8 slots x2
//      = 2 lanes/bank = conflict-free. Staging is lane-linear (chunk c at
//      byte c*16); global source pre-permuted via the inverse map.
// Pipeline: STAGE(t+2) during tile t; boundary s_waitcnt vmcnt(4) retires
// tile t+1's 4 loads, leaves t+2's in flight. Buffers distinct mod 4.
// ---------------------------------------------------------------------------
template<bool BIAS, bool OBF16>
__global__ __launch_bounds__(512, 2)
void gemm256(const ushort* __restrict__ A, const ushort* __restrict__ B,
             const float* __restrict__ bias, void* __restrict__ Cv,
             int K, int lda, int ldb, int ldc,
             long sAb, long sBb, long sCb)
{
    __shared__ char smem[131072];
    char* ldsA = smem;
    char* ldsB = smem + 65536;

    int z = blockIdx.z;
    const ushort* Ab = A + (size_t)sAb * z;
    const ushort* Bb = B + (size_t)sBb * z;
    size_t Coff = (size_t)sCb * z;

    // XCD-aware bijective workgroup swizzle (nwg % 8 == 0 for all our grids)
    int nwgx = gridDim.x;
    int nwg = nwgx * gridDim.y;
    int wg = blockIdx.y * nwgx + blockIdx.x;
    int swz = ((nwg & 7) == 0) ? (wg & 7) * (nwg >> 3) + (wg >> 3) : wg;
    int m0 = (swz % nwgx) * 256;
    int n0 = (swz / nwgx) * 256;

    int tid = threadIdx.x;
    int l = tid & 63, wid = tid >> 6;
    int wm = (wid >> 2) * 128;     // wave row: 0 or 128
    int wn = (wid & 3) * 64;       // wave col: 0/64/128/192
    int lr = l & 15, lj = l >> 4;  // frag: row-within-16 = lr, k-chunk = lj

    // fragment LDS byte offsets (within a 16KB tile block)
    int offA[8], offB[4];
#pragma unroll
    for (int m = 0; m < 8; m++) {
        int r = wm + m * 16 + lr;
        offA[m] = (r >> 1) * 128 + (((((r & 1) << 2) | lj) ^ ((r >> 1) & 7)) << 4);
    }
#pragma unroll
    for (int n = 0; n < 4; n++) {
        int r = wn + n * 16 + lr;
        offB[n] = (r >> 1) * 128 + (((((r & 1) << 2) | lj) ^ ((r >> 1) & 7)) << 4);
    }

    // staging: 2 chunks per operand per thread; chunk c -> logical (r,j) via
    // inverse of the swizzle (verified bijective: pos = up ^ (pr&7)).
    size_t srcA[2], srcB[2];
    int dstOff[2];
#pragma unroll
    for (int s = 0; s < 2; s++) {
        int c = tid + s * 512;
        int pr = c >> 3;
        int up = (c & 7) ^ (pr & 7);
        int r = (pr << 1) | (up >> 2);
        int jj = up & 3;
        srcA[s] = (size_t)(m0 + r) * lda + jj * 8;
        srcB[s] = (size_t)(n0 + r) * ldb + jj * 8;
        dstOff[s] = c * 16;
    }

    f32x4 acc[8][4];
#pragma unroll
    for (int m = 0; m < 8; m++)
#pragma unroll
        for (int n = 0; n < 4; n++)
            acc[m][n] = (f32x4){0.f, 0.f, 0.f, 0.f};

    int NT2 = K >> 5;   // K-tiles of 32

#define STAGE256(T) { int _bo = ((T) & 3) * 16384; size_t _ko = (size_t)(T) * 32; \
    gload_lds16(Ab + srcA[0] + _ko, ldsA + _bo + dstOff[0]); \
    gload_lds16(Ab + srcA[1] + _ko, ldsA + _bo + dstOff[1]); \
    gload_lds16(Bb + srcB[0] + _ko, ldsB + _bo + dstOff[0]); \
    gload_lds16(Bb + srcB[1] + _ko, ldsB + _bo + dstOff[1]); }

    STAGE256(0);
    STAGE256(1);
    asm volatile("s_waitcnt vmcnt(4)" ::: "memory");   // tile 0 resident
    __builtin_amdgcn_s_barrier();

    for (int t = 0; t < NT2; ++t) {
        if (t + 2 < NT2) {
            STAGE256(t + 2);
            __builtin_amdgcn_sched_barrier(0);   // keep prefetch issued early
        }
        int bo = (t & 3) * 16384;
        bf16x8s bf[4];
#pragma unroll
        for (int n = 0; n < 4; n++)
            bf[n] = *(const bf16x8s*)(ldsB + bo + offB[n]);
        bf16x8s af[8];
#pragma unroll
        for (int m = 0; m < 8; m++)
            af[m] = *(const bf16x8s*)(ldsA + bo + offA[m]);
#pragma unroll
        for (int m = 0; m < 8; m++)
#pragma unroll
            for (int n = 0; n < 4; n++)
                acc[m][n] = __builtin_amdgcn_mfma_f32_16x16x32_bf16(
                    af[m], bf[n], acc[m][n], 0, 0, 0);
        if (t + 1 < NT2) {
            if (t + 2 < NT2) asm volatile("s_waitcnt vmcnt(4)" ::: "memory");
            else             asm volatile("s_waitcnt vmcnt(0)" ::: "memory");
            __builtin_amdgcn_s_barrier();
        }
    }
#undef STAGE256

    // epilogue: C/D map col = lane&15, row = (lane>>4)*4 + reg
    int rr = lj * 4;
#pragma unroll
    for (int m = 0; m < 8; m++) {
#pragma unroll
        for (int n = 0; n < 4; n++) {
            int gr = m0 + wm + m * 16 + rr;
            int gc = n0 + wn + n * 16 + lr;
            float bv = BIAS ? bias[gc] : 0.f;
#pragma unroll
            for (int r = 0; r < 4; r++) {
                float v = acc[m][n][r] + bv;
                size_t off = Coff + (size_t)(gr + r) * ldc + gc;
                if (OBF16) ((ushort*)Cv)[off] = f2bf(v);
                else       ((float*)Cv)[off]  = v;
            }
        }
    }
}

// ---------------------------------------------------------------------------
// Old 128x128 NT GEMM (m97 structure) - kept for the tiny NT step (K=128).
// ---------------------------------------------------------------------------
template<bool BIAS, bool OBF16, int BN>
__global__ __launch_bounds__(256)
void gemm_nt(const ushort* __restrict__ A, const ushort* __restrict__ B,
             const float* __restrict__ bias, void* __restrict__ Cv,
             int K, int lda, int ldb, int ldc, int ZH,
             long sAb, long sAh, long sBb, long sBh, long sCb, long sCh)
{
    __shared__ ushort As[128 * 32];
    __shared__ ushort Bs[BN * 32];

    int z  = blockIdx.z;
    int zb = z / ZH, zh = z - zb * ZH;
    const ushort* Ab = A + (size_t)(sAb * zb + sAh * zh);
    const ushort* Bb = B + (size_t)(sBb * zb + sBh * zh);
    size_t Coff = (size_t)(sCb * zb + sCh * zh);

    int m0 = blockIdx.x * 128, n0 = blockIdx.y * BN;
    int t = threadIdx.x;
    int l = t & 63, w = t >> 6;
    int wm, wn;
    if (BN == 128) { wm = (w >> 1) * 64; wn = (w & 1) * 64; }
    else           { wm = w * 32;        wn = 0; }
    constexpr int FM = (BN == 128) ? 4 : 2;
    constexpr int FN = 4;
    int lr = l & 15, lk = (l >> 4) * 8;

    f32x4 acc[FM][FN];
#pragma unroll
    for (int i = 0; i < FM; i++)
#pragma unroll
        for (int j = 0; j < FN; j++)
            acc[i][j] = (f32x4){0.f, 0.f, 0.f, 0.f};

    int c0 = t, c1 = t + 256;
    int r0 = c0 >> 2, k0c = (c0 & 3) * 8;
    int r1 = c1 >> 2, k1c = (c1 & 3) * 8;

    for (int kt = 0; kt < K; kt += 32) {
        __syncthreads();
        gload_lds16(Ab + (size_t)(m0 + r0) * lda + kt + k0c, &As[c0 * 8]);
        gload_lds16(Ab + (size_t)(m0 + r1) * lda + kt + k1c, &As[c1 * 8]);
        gload_lds16(Bb + (size_t)(n0 + r0) * ldb + kt + k0c, &Bs[c0 * 8]);
        if (BN == 128)
            gload_lds16(Bb + (size_t)(n0 + r1) * ldb + kt + k1c, &Bs[c1 * 8]);
        __syncthreads();

        bf16x8s af[FM], bf[FN];
#pragma unroll
        for (int i = 0; i < FM; i++)
            af[i] = *(const bf16x8s*)&As[(wm + i * 16 + lr) * 32 + lk];
#pragma unroll
        for (int i = 0; i < FN; i++)
            bf[i] = *(const bf16x8s*)&Bs[(wn + i * 16 + lr) * 32 + lk];
#pragma unroll
        for (int mi = 0; mi < FM; mi++)
#pragma unroll
            for (int ni = 0; ni < FN; ni++)
                acc[mi][ni] = __builtin_amdgcn_mfma_f32_16x16x32_bf16(
                    af[mi], bf[ni], acc[mi][ni], 0, 0, 0);
    }

    int rr = (l >> 4) * 4;
#pragma unroll
    for (int mi = 0; mi < FM; mi++) {
#pragma unroll
        for (int ni = 0; ni < FN; ni++) {
            int gr = m0 + wm + mi * 16 + rr;
            int gc = n0 + wn + ni * 16 + lr;
            float bv = BIAS ? bias[gc] : 0.f;
#pragma unroll
            for (int r = 0; r < 4; r++) {
                float v = acc[mi][ni][r] + bv;
                size_t off = Coff + (size_t)(gr + r) * ldc + gc;
                if (OBF16) ((ushort*)Cv)[off] = f2bf(v);
                else       ((float*)Cv)[off]  = v;
            }
        }
    }
}

// ---------------------------------------------------------------------------
// RoPE on bf16 QKV buffer [4096][6144] (Q cols 0-2047, K 2048-4095).
// Q -> compact QB [4096][2048]; K in place.
// ---------------------------------------------------------------------------
__global__ __launch_bounds__(256)
void rope_qk(ushort* __restrict__ QKV, const int* __restrict__ pos,
             ushort* __restrict__ QB)
{
    int tid = blockIdx.x * 256 + threadIdx.x;   // 4096*16*8 = 524288
    int row = tid >> 7;
    int r = tid & 127;
    int h = r >> 3, j = r & 7;
    int d0 = j * 8;
    float p = (float)pos[row];
    size_t qb = (size_t)row * 6144 + h * 128 + d0;

    bf16x8s q1 = *(const bf16x8s*)&QKV[qb];
    bf16x8s q2 = *(const bf16x8s*)&QKV[qb + 64];
    bf16x8s k1 = *(const bf16x8s*)&QKV[qb + 2048];
    bf16x8s k2 = *(const bf16x8s*)&QKV[qb + 2048 + 64];
    bf16x8s oq1, oq2, ok1, ok2;
#pragma unroll
    for (int i = 0; i < 8; i++) {
        float d = (float)(d0 + i);
        float ang = p * exp2f(d * (-13.287712379549449f / 64.0f));
        float s, c;
        sincosf(ang, &s, &c);
        float a = b2f((ushort)q1[i]), b = b2f((ushort)q2[i]);
        oq1[i] = (short)f2bf(a * c - b * s);
        oq2[i] = (short)f2bf(b * c + a * s);
        float e = b2f((ushort)k1[i]), f = b2f((ushort)k2[i]);
        ok1[i] = (short)f2bf(e * c - f * s);
        ok2[i] = (short)f2bf(f * c + e * s);
    }
    size_t ob = (size_t)row * 2048 + h * 128 + d0;
    *(bf16x8s*)&QB[ob]      = oq1;
    *(bf16x8s*)&QB[ob + 64] = oq2;
    *(bf16x8s*)&QKV[qb + 2048]      = ok1;
    *(bf16x8s*)&QKV[qb + 2048 + 64] = ok2;
}

// ---------------------------------------------------------------------------
// K^T V partials from bf16 QKV buf. grid (32 bh, 16 s-slices).
// part[(slice*32 + bh)*16384 + d1*128 + d2]  (fp32, lives in d_out)
// ---------------------------------------------------------------------------
__global__ __launch_bounds__(256)
void ktv_partial(const ushort* __restrict__ QKV, float* __restrict__ part)
{
    int bh = blockIdx.x;
    int b = bh >> 4, h = bh & 15;
    int s0 = blockIdx.y * 128;
    const ushort* Kp = QKV + (size_t)(b * 2048 + s0) * 6144 + 2048 + h * 128;
    const ushort* Vp = Kp + 2048;

    __shared__ ushort Ks[32][128];
    __shared__ ushort Vs[32][128];

    int t = threadIdx.x;
    int tx = t & 15, ty = t >> 4;
    float acc[8][8];
#pragma unroll
    for (int i = 0; i < 8; i++)
#pragma unroll
        for (int j = 0; j < 8; j++) acc[i][j] = 0.f;

    for (int sb = 0; sb < 128; sb += 32) {
        __syncthreads();
#pragma unroll
        for (int i = 0; i < 2; i++) {
            int idx = t + i * 256;
            int rw = idx >> 4, c8 = (idx & 15) * 8;
            *(bf16x8s*)&Ks[rw][c8] = *(const bf16x8s*)&Kp[(size_t)(sb + rw) * 6144 + c8];
            *(bf16x8s*)&Vs[rw][c8] = *(const bf16x8s*)&Vp[(size_t)(sb + rw) * 6144 + c8];
        }
        __syncthreads();
        for (int ss = 0; ss < 32; ss++) {
            bf16x8s kvv = *(const bf16x8s*)&Ks[ss][tx * 8];
            bf16x8s vvv = *(const bf16x8s*)&Vs[ss][ty * 8];
            float kv[8], vv[8];
#pragma unroll
            for (int i = 0; i < 8; i++) { kv[i] = b2f((ushort)kvv[i]); vv[i] = b2f((ushort)vvv[i]); }
#pragma unroll
            for (int i = 0; i < 8; i++)
#pragma unroll
                for (int j = 0; j < 8; j++)
                    acc[i][j] += kv[i] * vv[j];
        }
    }
    float* pp = part + ((size_t)blockIdx.y * 32 + bh) * 16384;
#pragma unroll
    for (int i = 0; i < 8; i++)
#pragma unroll
        for (int j = 0; j < 8; j++)
            pp[(tx * 8 + i) * 128 + (ty * 8 + j)] = acc[i][j];
}

// Reduce 16 partials -> Mb (bf16), scaled by 1/sqrt(128).
__global__ __launch_bounds__(256)
void reduce_ktv(const float* __restrict__ part, ushort* __restrict__ Mb)
{
    int i = blockIdx.x * 256 + threadIdx.x;   // 32*16384 = 524288
    float s = 0.f;
#pragma unroll
    for (int p = 0; p < 16; p++) s += part[(size_t)p * 524288 + i];
    Mb[i] = f2bf(s * 0.08838834764831845f);
}

// fp32 -> bf16 convert, float4-vectorized (hidden states).
__global__ __launch_bounds__(256)
void conv_f32_bf16(const float* __restrict__ in, ushort* __restrict__ out, int n4)
{
    int i = blockIdx.x * 256 + threadIdx.x;
    if (i >= n4) return;
    float4 v = ((const float4*)in)[i];
    ushort4 o;
    o.x = f2bf(v.x); o.y = f2bf(v.y); o.z = f2bf(v.z); o.w = f2bf(v.w);
    ((ushort4*)out)[i] = o;
}

// All four weights -> bf16 in one launch (Wq,Wk,Wv stacked, Wo separate).
__global__ __launch_bounds__(256)
void conv_weights(const float* __restrict__ w0, const float* __restrict__ w1,
                  const float* __restrict__ w2, const float* __restrict__ w3,
                  ushort* __restrict__ qkv, ushort* __restrict__ wo)
{
    int i = blockIdx.x * 256 + threadIdx.x;
    int id = i >> 20;
    int off = i & 1048575;
    const float* src = (id == 0) ? w0 : (id == 1) ? w1 : (id == 2) ? w2 : w3;
    float4 v = ((const float4*)src)[off];
    ushort4 o;
    o.x = f2bf(v.x); o.y = f2bf(v.y); o.z = f2bf(v.z); o.w = f2bf(v.w);
    if (id < 3) ((ushort4*)qkv)[(size_t)id * 1048576 + off] = o;
    else        ((ushort4*)wo)[off] = o;
}

// Stack bq,bk,bv -> 6144-float buffer.
__global__ __launch_bounds__(256)
void pack_bias(const float* __restrict__ bq, const float* __restrict__ bk,
               const float* __restrict__ bv, float* __restrict__ bqkv)
{
    int i = blockIdx.x * 256 + threadIdx.x;
    float v = (i < 2048) ? bq[i] : (i < 4096) ? bk[i - 2048] : bv[i - 4096];
    bqkv[i] = v;
}

// ---------------------------------------------------------------------------
// Workspace (~102 MB): same layout as round 3.
//   HSB/QB @ 0        : 16,777,216   WQKV/NT @ 16777216 : 25,165,824
//   WOB @ 41943040 : 8,388,608       BQKV @ 50331648 : 24,576
//   QKVB @ 50356224 : 50,331,648     MB @ 100687872 : 1,048,576
// d_out doubles as ktv-partial scratch; final GEMM writes it last.
// ---------------------------------------------------------------------------
extern "C" void kernel_launch(void* const* d_in, const int* in_sizes, int n_in,
                              void* d_out, int out_size, void* d_ws, size_t ws_size,
                              hipStream_t stream)
{
    const float* hs = (const float*)d_in[0];
    const int*  pos = (const int*)d_in[1];
    const float* Wq = (const float*)d_in[2];
    const float* bq = (const float*)d_in[3];
    const float* Wk = (const float*)d_in[4];
    const float* bk = (const float*)d_in[5];
    const float* Wv = (const float*)d_in[6];
    const float* bv = (const float*)d_in[7];
    const float* Wo = (const float*)d_in[8];
    float* out = (float*)d_out;
    char* ws = (char*)d_ws;

    ushort* HSB  = (ushort*)(ws + 0);
    ushort* QB   = (ushort*)(ws + 0);           // HSB dead after QKV GEMM
    ushort* WQKV = (ushort*)(ws + 16777216);
    ushort* NT   = (ushort*)(ws + 16777216);    // WQKV dead after QKV GEMM
    ushort* WOB  = (ushort*)(ws + 41943040);
    float*  BQKV = (float*)(ws + 50331648);
    ushort* QKVB = (ushort*)(ws + 50356224);
    ushort* MB   = (ushort*)(ws + 100687872);
    float*  PART = out;                          // d_out as scratch until final

    dim3 blk(256);

    conv_f32_bf16<<<8192, blk, 0, stream>>>(hs, HSB, 2097152);
    conv_weights<<<16384, blk, 0, stream>>>(Wq, Wk, Wv, Wo, WQKV, WOB);
    pack_bias<<<24, blk, 0, stream>>>(bq, bk, bv, BQKV);

    // Fused QKV: [4096x2048] @ [6144x2048]^T -> QKVB [4096][6144] bf16
    gemm256<true, true><<<dim3(16, 24, 1), dim3(512), 0, stream>>>(
        HSB, WQKV, BQKV, QKVB, 2048, 2048, 2048, 6144, 0, 0, 0);

    rope_qk<<<2048, blk, 0, stream>>>(QKVB, pos, QB);

    ktv_partial<<<dim3(32, 16, 1), blk, 0, stream>>>(QKVB, PART);
    reduce_ktv<<<2048, blk, 0, stream>>>(PART, MB);

    // NT_b[j][h*128+d1] = sum_d2 Wo_b16[j][h*128+d2] * M_bh[d1][d2]
    gemm_nt<false, true, 128><<<dim3(16, 1, 32), blk, 0, stream>>>(
        WOB, MB, nullptr, NT, 128, 2048, 128, 2048, 16,
        0, 128, 262144, 16384, 4194304, 128);

    // out[b] = QB_b @ NT_b^T
    gemm256<false, false><<<dim3(8, 8, 2), dim3(512), 0, stream>>>(
        QB, NT, nullptr, out, 2048, 2048, 2048, 2048,
        4194304, 4194304, 4194304);
}